// Round 8
// baseline (16970.894 us; speedup 1.0000x reference)
//
#include <hip/hip_runtime.h>
#include <hip/hip_bf16.h>

// 2-layer LSTM, B=64, F=128, T=1024, H=512. Output = h_T of layer 1 (64x512 fp32).
// R8: BARRIER-FREE in-data signaling. Evidence (R2..R7): best-case 7.9us/iter is
// invariant to weights location / WG count / poller count / fence presence ->
// the drain+flag+poll+barrier skeleton IS the floor (R6: one extra hop = +1.2us;
// WRITE_SIZE 518KB/iter shows sc-bypass publishes drain to HBM, so the pre-flag
// vmcnt(0) waits on DRAM acks). This round deletes the skeleton:
//  - h published as u64 atoms {bf16 col-pair, u32 epoch} via relaxed agent-scope
//    atomic stores (single-copy atomic: data+seq arrive together -> no fence, no
//    flag, no drain, no global barrier anywhere in the loop).
//  - readers poll each u64 for seq >= epoch with a rolling 4-chunk window feeding
//    MFMA (loads pipeline across the ~600cyc L3 RTT; stale chunks re-polled).
//  - 8-slot generation rotation. WAR safety: L0 WGs self-sync within 1 iter via
//    h0 reads; L1 <= L0+1; L0 <= L1+2 enforced by a 1-u64 backpressure probe on
//    h1(it-2). L1 pre-publishes h1(0)=0 (seq 1) in its prologue.
//  - WGs free-run: inter-iteration overlap instead of a 256-WG convoy.
// Kept from R4: 256 WGs x 256 thr layer-split, weights in registers, tiny LDS
// gate reshuffle, x prefetch, bf16 numerics (absmax 4.88e-4, 4x margin).

#define B_ 64
#define F_ 128
#define T_ 1024
#define H_ 512
#define NWG 256
#define SLOTN (B_ * (H_ / 2))   // u64s per slot: 64 batches x 256 col-pairs

typedef __bf16 bf16x8 __attribute__((ext_vector_type(8)));
typedef float f32x4 __attribute__((ext_vector_type(4)));
typedef unsigned long long u64;

__device__ __forceinline__ float sigm(float x) { return 1.0f / (1.0f + __expf(-x)); }
__device__ __forceinline__ float tanh_fast(float x) { return 1.0f - 2.0f / (__expf(2.0f * x) + 1.0f); }

__device__ __forceinline__ u64 ld_seq(const u64* p) {
  return __hip_atomic_load(p, __ATOMIC_RELAXED, __HIP_MEMORY_SCOPE_AGENT);
}
__device__ __forceinline__ void st_seq(u64* p, u64 v) {
  __hip_atomic_store(p, v, __ATOMIC_RELAXED, __HIP_MEMORY_SCOPE_AGENT);
}

// Rolling-window stream: 16 chunks x 4 u64; each u64 = {2 bf16 (low), seq (high)}.
// Wait per-chunk until all 4 seqs >= tgt, then MFMA with weight frag w[kc].
__device__ __forceinline__ void mfma_stream(const u64* __restrict__ hq, int addr0,
                                            unsigned tgt, const bf16x8* w, f32x4& acc) {
  u64 win[4][4];
#pragma unroll
  for (int kc = 0; kc < 4; ++kc)
#pragma unroll
    for (int j = 0; j < 4; ++j) win[kc][j] = ld_seq(hq + addr0 + kc * 16 + j);
#pragma unroll
  for (int kc = 0; kc < 16; ++kc) {
    u64* W = win[kc & 3];
    while (!((unsigned)(W[0] >> 32) >= tgt && (unsigned)(W[1] >> 32) >= tgt &&
             (unsigned)(W[2] >> 32) >= tgt && (unsigned)(W[3] >> 32) >= tgt)) {
#pragma unroll
      for (int j = 0; j < 4; ++j) W[j] = ld_seq(hq + addr0 + kc * 16 + j);
    }
    union { unsigned d[4]; bf16x8 v; } u;
#pragma unroll
    for (int j = 0; j < 4; ++j) u.d[j] = (unsigned)W[j];
    acc = __builtin_amdgcn_mfma_f32_16x16x32_bf16(w[kc], u.v, acc, 0, 0, 0);
    if (kc + 4 < 16) {
#pragma unroll
      for (int j = 0; j < 4; ++j) W[j] = ld_seq(hq + addr0 + (kc + 4) * 16 + j);
    }
  }
}

// x (B,F,T) fp32 -> xT (T,B,F) bf16
__global__ __launch_bounds__(256) void transpose_x_kernel(const float* __restrict__ x,
                                                          __bf16* __restrict__ xT) {
  __shared__ float tile[F_][65];
  const int bb = blockIdx.x >> 4;
  const int tt = blockIdx.x & 15;
  const int tid = threadIdx.x;
  const int tl = tid & 63;
  const int f0 = tid >> 6;
  for (int fo = 0; fo < F_; fo += 4) {
    int f = fo + f0;
    tile[f][tl] = x[((size_t)bb * F_ + f) * T_ + tt * 64 + tl];
  }
  __syncthreads();
  const int fw = tid & 127;
  const int tg = tid >> 7;
  for (int to = 0; to < 64; to += 2) {
    int t = to + tg;
    xT[((size_t)(tt * 64 + t) * B_ + bb) * F_ + fw] = (__bf16)tile[fw][t];
  }
}

__global__ __launch_bounds__(256, 1) void lstm_persistent(
    const __bf16* __restrict__ xT,
    const float* __restrict__ Wih0, const float* __restrict__ Whh0,
    const float* __restrict__ bih0, const float* __restrict__ bhh0,
    const float* __restrict__ Wih1, const float* __restrict__ Whh1,
    const float* __restrict__ bih1, const float* __restrict__ bhh1,
    u64* hq0, u64* hq1,             // each: [8][B][H/2] u64 {bf16 pair, epoch}
    float* __restrict__ out) {
  __shared__ float sG[4][272];   // gate reshuffle staging, stride 68 (conflict-free)

  const int wg   = blockIdx.x;
  const int tid  = threadIdx.x;
  const int wv   = tid >> 6;
  const int lane = tid & 63;
  const int p    = lane >> 4;        // quad
  const int l15  = lane & 15;
  const int b    = wv * 16 + l15;    // batch
  const int ks   = p * 8;            // k offset inside a 32-chunk
  const int col4 = (wg & 127) * 4;   // this WG's 4 h-columns
  const int row  = (l15 >> 2) * H_ + col4 + (l15 & 3);  // A-frag gate row for m=l15
  const int raddr0 = b * (H_ / 2) + p * 4;              // reader u64 base (chunk 0)
  const int widx   = b * (H_ / 2) + (col4 >> 1) + (p >> 1);  // writer u64 index

  if (wg < 128) {
    // ---------------- layer 0 ----------------
    bf16x8 wh[16], wi[4];
    {
      const float* s = Whh0 + (size_t)row * H_ + ks;
#pragma unroll
      for (int kc = 0; kc < 16; ++kc) {
        bf16x8 a;
#pragma unroll
        for (int j = 0; j < 8; ++j) a[j] = (__bf16)s[kc * 32 + j];
        wh[kc] = a;
      }
      const float* si = Wih0 + (size_t)row * F_ + ks;
#pragma unroll
      for (int kc = 0; kc < 4; ++kc) {
        bf16x8 a;
#pragma unroll
        for (int j = 0; j < 8; ++j) a[j] = (__bf16)si[kc * 32 + j];
        wi[kc] = a;
      }
    }
    float bq[4];
#pragma unroll
    for (int r = 0; r < 4; ++r) {
      const int grow = p * H_ + col4 + r;
      bq[r] = bih0[grow] + bhh0[grow];
    }

    float c0 = 0.f;
    for (int it = 0; it < T_; ++it) {
      // x frags for this step (cached loads; issued before the h stream -> overlap)
      const __bf16* xrow = xT + ((size_t)it * B_ + b) * F_;
      bf16x8 xb[4];
#pragma unroll
      for (int kc = 0; kc < 4; ++kc) xb[kc] = *(const bf16x8*)&xrow[kc * 32 + ks];

      f32x4 acc  = {0.f, 0.f, 0.f, 0.f};
      f32x4 acc2 = {0.f, 0.f, 0.f, 0.f};
      // h0(it-1): slot (it-1)&7, epoch it (memset-zero slot 7 passes tgt=0 at it=0)
      mfma_stream(hq0 + (size_t)((it + 7) & 7) * SLOTN, raddr0, (unsigned)it, wh, acc);
#pragma unroll
      for (int kc = 0; kc < 4; ++kc)
        acc2 = __builtin_amdgcn_mfma_f32_16x16x32_bf16(wi[kc], xb[kc], acc2, 0, 0, 0);

#pragma unroll
      for (int r = 0; r < 4; ++r) {
        float v = acc[r] + acc2[r] + bq[r];
        sG[wv][p * 68 + r * 16 + l15] = (p == 2) ? tanh_fast(v) : sigm(v);
      }
      __syncthreads();
      float gi = sG[wv][0 * 68 + p * 16 + l15];
      float gf = sG[wv][1 * 68 + p * 16 + l15];
      float gg = sG[wv][2 * 68 + p * 16 + l15];
      float go = sG[wv][3 * 68 + p * 16 + l15];
      c0 = gf * c0 + gi * gg;
      float h = go * tanh_fast(c0);
      __syncthreads();   // sG reusable next iter

      union { __bf16 bf; unsigned short u; } cv; cv.bf = (__bf16)h;
      unsigned o = (unsigned)__shfl_xor((int)(unsigned)cv.u, 16, 64);
      if ((p & 1) == 0) {
        // backpressure: h1(it-2) must exist (epoch it-1) before overwriting slot it&7
        if (it >= 2) {
          const u64* bp = hq1 + (size_t)((it - 2) & 7) * SLOTN + widx;
          while ((unsigned)(ld_seq(bp) >> 32) < (unsigned)(it - 1))
            __builtin_amdgcn_s_sleep(1);
        }
        u64 val = (u64)((unsigned)cv.u | (o << 16)) | ((u64)(unsigned)(it + 1) << 32);
        st_seq(hq0 + (size_t)(it & 7) * SLOTN + widx, val);
      }
    }
  } else {
    // ---------------- layer 1 ----------------
    bf16x8 wi[16], wh[16];
    {
      const float* s0 = Wih1 + (size_t)row * H_ + ks;
      const float* s1 = Whh1 + (size_t)row * H_ + ks;
#pragma unroll
      for (int kc = 0; kc < 16; ++kc) {
        bf16x8 a, c;
#pragma unroll
        for (int j = 0; j < 8; ++j) {
          a[j] = (__bf16)s0[kc * 32 + j];
          c[j] = (__bf16)s1[kc * 32 + j];
        }
        wi[kc] = a; wh[kc] = c;
      }
    }
    float bq[4];
#pragma unroll
    for (int r = 0; r < 4; ++r) {
      const int grow = p * H_ + col4 + r;
      bq[r] = bih1[grow] + bhh1[grow];
    }

    // pre-publish h1(0) = 0 with epoch 1 (nobody computes it; readers need it at it=1;
    // L0's backpressure probe needs it at it=2)
    if ((p & 1) == 0)
      st_seq(hq1 + 0 * SLOTN + widx, (u64)1 << 32);

    float c1 = 0.f;
    for (int it = 1; it <= T_; ++it) {
      f32x4 acca = {0.f, 0.f, 0.f, 0.f};
      f32x4 accc = {0.f, 0.f, 0.f, 0.f};
      const size_t rs = (size_t)((it - 1) & 7) * SLOTN;
      mfma_stream(hq0 + rs, raddr0, (unsigned)it, wi, acca);   // h0(it-1)
      mfma_stream(hq1 + rs, raddr0, (unsigned)it, wh, accc);   // h1(it-1)

#pragma unroll
      for (int r = 0; r < 4; ++r) {
        float v = acca[r] + accc[r] + bq[r];
        sG[wv][p * 68 + r * 16 + l15] = (p == 2) ? tanh_fast(v) : sigm(v);
      }
      __syncthreads();
      float gi = sG[wv][0 * 68 + p * 16 + l15];
      float gf = sG[wv][1 * 68 + p * 16 + l15];
      float gg = sG[wv][2 * 68 + p * 16 + l15];
      float go = sG[wv][3 * 68 + p * 16 + l15];
      c1 = gf * c1 + gi * gg;
      float h = go * tanh_fast(c1);
      __syncthreads();   // sG reusable next iter

      if (it < T_) {
        union { __bf16 bf; unsigned short u; } cv; cv.bf = (__bf16)h;
        unsigned o = (unsigned)__shfl_xor((int)(unsigned)cv.u, 16, 64);
        if ((p & 1) == 0) {
          u64 val = (u64)((unsigned)cv.u | (o << 16)) | ((u64)(unsigned)(it + 1) << 32);
          st_seq(hq1 + (size_t)(it & 7) * SLOTN + widx, val);
        }
      } else {
        out[b * H_ + col4 + p] = h;   // final h1[T-1], fp32
      }
    }
  }
}

// Workspace layout:
//   [0]        hq0: 8 slots x 16384 u64 x 8B = 1 MiB
//   [1 MiB]    hq1: 1 MiB
//   [2 MiB]    xT: 16 MiB
// Zeroed region: [0, 2 MiB) — seq fields MUST be 0 (ws is poisoned 0xAA).
extern "C" void kernel_launch(void* const* d_in, const int* in_sizes, int n_in,
                              void* d_out, int out_size, void* d_ws, size_t ws_size,
                              hipStream_t stream) {
  const float* x    = (const float*)d_in[0];
  const float* Wih0 = (const float*)d_in[1];
  const float* Whh0 = (const float*)d_in[2];
  const float* bih0 = (const float*)d_in[3];
  const float* bhh0 = (const float*)d_in[4];
  const float* Wih1 = (const float*)d_in[5];
  const float* Whh1 = (const float*)d_in[6];
  const float* bih1 = (const float*)d_in[7];
  const float* bhh1 = (const float*)d_in[8];
  float* out = (float*)d_out;

  char* ws = (char*)d_ws;
  u64* hq0 = (u64*)ws;
  u64* hq1 = (u64*)(ws + (1 << 20));
  __bf16* xT = (__bf16*)(ws + (2 << 20));

  hipMemsetAsync(ws, 0, 2 << 20, stream);

  transpose_x_kernel<<<dim3(B_ * 16), dim3(256), 0, stream>>>(x, xT);

  lstm_persistent<<<dim3(NWG), dim3(256), 0, stream>>>(
      xT, Wih0, Whh0, bih0, bhh0, Wih1, Whh1, bih1, bhh1,
      hq0, hq1, out);
}